// Round 6
// baseline (145.947 us; speedup 1.0000x reference)
//
#include <hip/hip_runtime.h>

// SSIM loss via separable 11-tap Gaussian, both conv passes on matrix cores
// (v_mfma_f32_16x16x32_f16). R16 = R15 body at 512 threads/block (8 waves).
// R15 was residency-bound: no pipe >40% (VALU 36, HBM 12.5, Mfma 6.5),
// occupancy 46% = 14.7 waves avg vs 24-wave cap (6 blocks x 4 waves).
//  - 512-thread blocks: wave-slot cap becomes 4 blocks x 8 waves = 32
//    resident waves (+33%). REQUIRES VGPR <= 64 (__launch_bounds__(512,8));
//    B-register-cache trimmed to 1 item/wave to protect the budget.
//  - Tap PAIR-table tbp[64]: tbp[k] = (tap(k-19), tap(k-18)) f16x2. A lane's
//    8-tap fragment window is contiguous in t -> 4 b32 reads at stride 2,
//    ~2 lanes/bank (old tb gather was provably 4-way: u-parity constant
//    across the 4 lanes sharing a column). Halves frag LDS reads, kills
//    the residual conflict source, drops 16 cvts.
// Reduction history (hard-won, do NOT re-fuse): R13 fence+acq_rel fused
// reduction -> 9x regression (device-scope cache ops serialize retirement);
// R14 relaxed same-line atomics -> 3x slow (6144 RMWs on one line ping-pong
// across 8 XCDs). Two-kernel scheme (plain store + tiny reduce) is right.
// Body (verified R13-R15, all big wave64 LDS patterns at words/bank min):
//  - Geometry: x0=32bx-8 (48 staged cols), y0=64by-9 (80 rows); sx/sy
//    80x24 words col-pair f16; phase A = float4 -> cvt_pk -> ds_write_b64.
//  - Phase B: A-op = one ds_read_b128; taps t=k-lm-3 both col-tiles; bands
//    {0,16,32,48,64}; items i=wv,wv+8 (waves 0,1 take band 4).
//  - hq column-major [2][32][40]: b64 stores / b128 reads, bank-balanced.
//  - Phase C: per-wave quadrant rq=wv>>1 (rpb=8rq), ch=wv&1; taps t=k-lm-4;
//    acc[5], 4 px/lane. 3-chunk quantity loop ({x,y},{xx,yy},{xy}).
// LDS ~25.9KB; 4 blocks/CU (wave-slot capped). XCD-aware bijective swizzle.

typedef __fp16 f16x8 __attribute__((ext_vector_type(8)));
typedef float f32x4 __attribute__((ext_vector_type(4)));
typedef unsigned u32x4 __attribute__((ext_vector_type(4)));

__device__ __forceinline__ unsigned pk2(float a, float b) {
    return __builtin_bit_cast(unsigned, __builtin_amdgcn_cvt_pkrtz(a, b));
}
__device__ __forceinline__ f32x4 mfma16(f16x8 a, f16x8 b, f32x4 c) {
    return __builtin_amdgcn_mfma_f32_16x16x32_f16(a, b, c, 0, 0, 0);
}

#define SXW 24   // staged words/row (48 f16 cols), rows 16B-aligned
#define HRP 40   // hq row-pairs per column (80 staged rows)

__global__ __launch_bounds__(512, 8) void ssim_main(
    const float* __restrict__ xg, const float* __restrict__ yg,
    const float* __restrict__ w2d, float* __restrict__ part)
{
    __shared__ __align__(16) unsigned sx[80 * SXW];      // 7680 B
    __shared__ __align__(16) unsigned sy[80 * SXW];      // 7680 B
    __shared__ __align__(16) unsigned hq[2][32 * HRP];   // 10240 B
    __shared__ unsigned tbp[64];                         // 256 B pair-table
    __shared__ float gsf[12];
    __shared__ float wred[8];

    const int tid = threadIdx.x;

    // 1D kernel = row sums of the 2D window (outer(g,g), sum 1).
    if (tid < 12) {
        float s = 0.0f;
        if (tid < 11) {
            #pragma unroll
            for (int j = 0; j < 11; ++j) s += w2d[tid * 11 + j];
        }
        gsf[tid] = s;
    }

    // XCD-aware bijective swizzle (nwg = 128*Z, %8==0).
    const int nwg = 128 * (int)gridDim.z;
    const int flat = (int)blockIdx.x + 16 * ((int)blockIdx.y + 8 * (int)blockIdx.z);
    const int swz = (flat & 7) * (nwg >> 3) + (flat >> 3);
    const int bx = swz & 15, by = (swz >> 4) & 7, bz = swz >> 7;

    const int x0 = bx * 32 - 8;   // mult of 4 -> float4-aligned
    const int y0 = by * 64 - 9;
    const size_t zoff = (size_t)bz * (512 * 512);
    const float* __restrict__ xp = xg + zoff;
    const float* __restrict__ yp = yg + zoff;

    // Phase A: stage 80 rows x 12 float4-groups, zero-padded at edges.
    const bool interior = (x0 >= 0) & (x0 + 47 < 512) & (y0 >= 0) & (y0 + 79 < 512);
    if (interior) {
        for (int it = tid; it < 80 * 12; it += 512) {
            const int r = it / 12, c4 = it - r * 12;
            const int o = (y0 + r) * 512 + x0 + 4 * c4;
            const float4 vx = *(const float4*)&xp[o];
            const float4 vy = *(const float4*)&yp[o];
            *(uint2*)&sx[2 * it] = make_uint2(pk2(vx.x, vx.y), pk2(vx.z, vx.w));
            *(uint2*)&sy[2 * it] = make_uint2(pk2(vy.x, vy.y), pk2(vy.z, vy.w));
        }
    } else {
        for (int it = tid; it < 80 * 12; it += 512) {
            const int r = it / 12, c4 = it - r * 12;
            const int gr = y0 + r, gc0 = x0 + 4 * c4;
            const bool rok = (unsigned)gr < 512u;
            float xv[4], yv[4];
            #pragma unroll
            for (int j = 0; j < 4; ++j) {
                const int gc = gc0 + j;
                const bool ok = rok & ((unsigned)gc < 512u);
                const int o = gr * 512 + gc;
                xv[j] = ok ? xp[o] : 0.f;
                yv[j] = ok ? yp[o] : 0.f;
            }
            *(uint2*)&sx[2 * it] = make_uint2(pk2(xv[0], xv[1]), pk2(xv[2], xv[3]));
            *(uint2*)&sy[2 * it] = make_uint2(pk2(yv[0], yv[1]), pk2(yv[2], yv[3]));
        }
    }
    __syncthreads();

    // Pair-table: tbp[k] = (tap(k-19), tap(k-18)) packed f16x2. Taps are
    // f16-rounded with center correction so the f16 tap sum ~= 1.
    if (tid < 64) {
        float ssum = 0.0f;
        #pragma unroll
        for (int k = 0; k < 11; ++k)
            if (k != 5) ssum += (float)(__fp16)gsf[k];
        const __fp16 cc = (__fp16)(1.0f - ssum);
        auto tap = [&](int t) -> __fp16 {
            if ((unsigned)t > 10u) return (__fp16)0.f;
            return (t == 5) ? cc : (__fp16)gsf[t];
        };
        const int t = tid - 19;
        const unsigned short lo = __builtin_bit_cast(unsigned short, tap(t));
        const unsigned short hi = __builtin_bit_cast(unsigned short, tap(t + 1));
        tbp[tid] = (unsigned)lo | ((unsigned)hi << 16);
    }
    __syncthreads();

    const int lane = tid & 63, wv = tid >> 6;      // wv in 0..7
    const int lm = lane & 15, lg = lane >> 4;

    // Tap fragments (k = 8*lg + e):
    //  Phase B (B operand, both tiles): t = k - lm - 3 -> base k0
    //  Phase C (A operand, all waves):  t = k - lm - 4 -> base k0-1
    f16x8 bt, afr;
    {
        const int k0 = 8 * lg - lm + 16;           // in [1,40]
        u32x4 wb, wa;
        #pragma unroll
        for (int i = 0; i < 4; ++i) {
            wb[i] = tbp[k0 + 2 * i];
            wa[i] = tbp[k0 - 1 + 2 * i];
        }
        bt  = __builtin_bit_cast(f16x8, wb);
        afr = __builtin_bit_cast(f16x8, wa);
    }

    // B-operand register cache: wave wv owns item wv; waves 0,1 also own
    // items 8,9 (band 4), re-read per chunk to keep VGPR <= 64.
    auto ldpair = [&](int i, f16x8& xa, f16x8& ya) {
        const int b = i >> 1, tl = i & 1;
        const int sbase = (16 * b + lm) * SXW + 8 * tl + 4 * lg;
        xa = __builtin_bit_cast(f16x8, *(const u32x4*)&sx[sbase]);
        ya = __builtin_bit_cast(f16x8, *(const u32x4*)&sy[sbase]);
    };
    f16x8 xa0, ya0;
    ldpair(wv, xa0, ya0);

    f32x4 acc[5];
    #pragma unroll
    for (int q = 0; q < 5; ++q) acc[q] = (f32x4){0.f, 0.f, 0.f, 0.f};

    const int rq = wv >> 1, ch = wv & 1;
    const int rpb = 8 * rq;   // hq rp base of the C-phase K window

    // Chunks over quantities: {x,y} -> {x*x,y*y} -> {x*y}, reusing hq[0..1].
    #pragma unroll
    for (int chunk = 0; chunk < 3; ++chunk) {
        auto bitem = [&](const f16x8& xa, const f16x8& ya, int i) {
            const int b = i >> 1, tl = i & 1;
            const f32x4 z4 = {0.f, 0.f, 0.f, 0.f};
            f32x4 d0 = z4, d1 = z4;
            if (chunk == 0)      { d0 = mfma16(xa, bt, z4);      d1 = mfma16(ya, bt, z4); }
            else if (chunk == 1) { d0 = mfma16(xa * xa, bt, z4); d1 = mfma16(ya * ya, bt, z4); }
            else                 { d0 = mfma16(xa * ya, bt, z4); }
            // D: col = lm (+16*tl), staged rows 16b+4lg+{0..3}
            //  -> rp = 8b+2lg, +1: contiguous in col-major hq -> ds_write_b64.
            const int ob = (16 * tl + lm) * HRP + 8 * b + 2 * lg;
            *(uint2*)&hq[0][ob] = make_uint2(pk2(d0[0], d0[1]), pk2(d0[2], d0[3]));
            if (chunk < 2)
                *(uint2*)&hq[1][ob] = make_uint2(pk2(d1[0], d1[1]), pk2(d1[2], d1[3]));
        };
        bitem(xa0, ya0, wv);
        if (wv < 2) {                          // wave-uniform branch
            f16x8 xf, yf;
            ldpair(wv + 8, xf, yf);
            bitem(xf, yf, wv + 8);
        }
        __syncthreads();

        // Phase C: vertical conv as MFMA into the chunk's accumulators.
        {
            const int cb = (16 * ch + lm) * HRP + rpb + 4 * lg;  // 16B aligned
            #pragma unroll
            for (int s = 0; s < 2; ++s) {
                if (chunk == 2 && s == 1) continue;
                const u32x4 w4 = *(const u32x4*)&hq[s][cb];
                acc[2 * chunk + s] =
                    mfma16(afr, __builtin_bit_cast(f16x8, w4), acc[2 * chunk + s]);
            }
        }
        if (chunk < 2) __syncthreads();   // hq reads done before next B rewrites
    }

    // SSIM epilogue: lane holds out col 16ch+lm, out rows 16rq+4lg+{0..3}.
    float lsum = 0.0f;
    const float C1 = 1e-4f, C2 = 9e-4f;
    #pragma unroll
    for (int r = 0; r < 4; ++r) {
        const float mx = acc[0][r], my = acc[1][r];
        const float exx = acc[2][r], eyy = acc[3][r];
        const float exy = acc[4][r];
        const float mx2 = mx * mx, my2 = my * my, mxy = mx * my;
        const float vx = exx - mx2, vy = eyy - my2, vxy = exy - mxy;
        const float num = (2.0f * mxy + C1) * (2.0f * vxy + C2);
        const float den = (mx2 + my2 + C1) * (vx + vy + C2) + 1e-12f;
        lsum = fmaf(num, __builtin_amdgcn_rcpf(den), lsum);
    }

    // Wave reduce -> cross-wave via LDS -> one plain store per block.
    #pragma unroll
    for (int off = 32; off > 0; off >>= 1)
        lsum += __shfl_down(lsum, off, 64);
    if ((tid & 63) == 0) wred[tid >> 6] = lsum;
    __syncthreads();
    if (tid == 0) {
        float s = 0.0f;
        #pragma unroll
        for (int w = 0; w < 8; ++w) s += wred[w];
        part[swz] = s;
    }
}

__global__ __launch_bounds__(256) void ssim_reduce(
    const float* __restrict__ part, float* __restrict__ out,
    int n, float invN)
{
    __shared__ float wred[4];
    float s = 0.0f;
    for (int i = threadIdx.x; i < n; i += 256) s += part[i];
    #pragma unroll
    for (int off = 32; off > 0; off >>= 1)
        s += __shfl_down(s, off, 64);
    if ((threadIdx.x & 63) == 0) wred[threadIdx.x >> 6] = s;
    __syncthreads();
    if (threadIdx.x == 0)
        out[0] = 1.0f - (wred[0] + wred[1] + wred[2] + wred[3]) * invN;
}

extern "C" void kernel_launch(void* const* d_in, const int* in_sizes, int n_in,
                              void* d_out, int out_size, void* d_ws, size_t ws_size,
                              hipStream_t stream) {
    const float* x   = (const float*)d_in[0];
    const float* y   = (const float*)d_in[1];
    const float* w2d = (const float*)d_in[2];  // (3,1,11,11); channels identical
    float* out  = (float*)d_out;
    float* part = (float*)d_ws;                // 6144 floats = 24 KB

    const int H = 512, W = 512;
    const int total = in_sizes[0];              // 16*3*512*512
    const int Z = total / (H * W);              // 48

    dim3 grid(W / 32, H / 64, Z);               // 16 x 8 x 48 = 6144 blocks
    const int nblk = (W / 32) * (H / 64) * Z;
    ssim_main<<<grid, 512, 0, stream>>>(x, y, w2d, part);

    const float invN = 1.0f / (float)total;
    ssim_reduce<<<1, 256, 0, stream>>>(part, out, nblk, invN);
}

// Round 7
// 143.049 us; speedup vs baseline: 1.0203x; 1.0203x over previous
//
#include <hip/hip_runtime.h>

// SSIM loss via separable 11-tap Gaussian, both conv passes on matrix cores
// (v_mfma_f32_16x16x32_f16). R17 = latency-structure rework. R16 proved
// occupancy is NOT the limiter (63% occ, 20 VGPR, same 50us as R15); all
// pipes idle -> per-block serialization: ~8 __syncthreads (each lowered
// with a full vmcnt(0) drain), fully-exposed phase-A HBM latency, and a
// 3-chunk loop tripling barrier count to save LDS we don't need to save.
//  - ldsBarrier(): s_waitcnt lgkmcnt(0); s_barrier (single asm, "memory").
//    Every barrier here orders LDS only -> never drain vmcnt. Prefetches
//    stay in flight across barriers.
//  - 2 tiles per block (grid 3072, x-adjacent pairs share halo in L2):
//    tile-1 global loads issue into VGPRs BEFORE tile-0's B/C; ds_writes
//    land after C(t0). ~900cyc HBM latency hides under ~2000cyc compute.
//  - Un-chunked: hq 5 slots (LDS 41.3KB -> 3 blocks x 8 waves = 24-wave
//    cap); barriers 16 -> 6 per 2 tiles; B-phase products from regs once.
// Reduction history (hard-won, do NOT re-fuse): R13 fences -> 9x slower;
// R14 same-line relaxed atomics -> 3x slower (XCD ping-pong). Two-kernel
// scheme (plain per-block store + tiny reduce) is correct.
// Body formulas (verified R13-R16, all big wave64 LDS patterns at the
// words/bank minimum):
//  - Geometry: x0=32bx-8 (48 staged cols), y0=64by-9 (80 rows); sx/sy
//    80x24 words col-pair f16; phase A = float4 -> cvt_pk -> ds_write_b64.
//  - Phase B: A-op = one ds_read_b128; taps t=k-lm-3 (pair-table tbp);
//    bands {0,16,32,48,64}; items i=wv (+8 for wv<2).
//  - hq column-major [5][32][40]: b64 stores / b128 reads, bank-balanced.
//  - Phase C: wave quadrant rq=wv>>1 (rpb=8rq), ch=wv&1; taps t=k-lm-4;
//    one MFMA per quantity; 4 px/lane epilogue.

typedef __fp16 f16x8 __attribute__((ext_vector_type(8)));
typedef float f32x4 __attribute__((ext_vector_type(4)));
typedef unsigned u32x4 __attribute__((ext_vector_type(4)));

__device__ __forceinline__ unsigned pk2(float a, float b) {
    return __builtin_bit_cast(unsigned, __builtin_amdgcn_cvt_pkrtz(a, b));
}
__device__ __forceinline__ f32x4 mfma16(f16x8 a, f16x8 b, f32x4 c) {
    return __builtin_amdgcn_mfma_f32_16x16x32_f16(a, b, c, 0, 0, 0);
}
// LDS-only barrier: orders LDS across waves WITHOUT draining vmcnt.
__device__ __forceinline__ void ldsBarrier() {
    asm volatile("s_waitcnt lgkmcnt(0)\n\ts_barrier" ::: "memory");
}

#define SXW 24   // staged words/row (48 f16 cols), rows 16B-aligned
#define HRP 40   // hq row-pairs per column (80 staged rows)

__global__ __launch_bounds__(512, 6) void ssim_main(
    const float* __restrict__ xg, const float* __restrict__ yg,
    const float* __restrict__ w2d, float* __restrict__ part)
{
    __shared__ __align__(16) unsigned sx[80 * SXW];      // 7680 B
    __shared__ __align__(16) unsigned sy[80 * SXW];      // 7680 B
    __shared__ __align__(16) unsigned hq[5][32 * HRP];   // 25600 B
    __shared__ unsigned tbp[64];                         // 256 B pair-table
    __shared__ float gsf[12];
    __shared__ float wred[8];

    const int tid = threadIdx.x;

    // 1D kernel = row sums of the 2D window (outer(g,g), sum 1).
    if (tid < 12) {
        float s = 0.0f;
        if (tid < 11) {
            #pragma unroll
            for (int j = 0; j < 11; ++j) s += w2d[tid * 11 + j];
        }
        gsf[tid] = s;
    }

    // Pair swizzle: 3072 pairs, XCD-bijective; block handles x-adjacent
    // tiles t0=2k, t1=2k+1 of the 6144-tile space (t&15 even/odd -> same
    // by,bz always).
    const int npair = 64 * (int)gridDim.z;
    const int flat = (int)blockIdx.x + 8 * ((int)blockIdx.y + 8 * (int)blockIdx.z);
    const int k = (flat & 7) * (npair >> 3) + (flat >> 3);
    const int t0 = 2 * k, t1 = 2 * k + 1;

    const int it0 = tid, it1 = tid + 512;
    const bool has1 = (it1 < 960);           // waves 0..6

    auto decode = [&](int t, int& x0, int& y0, const float*& xp,
                      const float*& yp, bool& inter) {
        const int bx = t & 15, by = (t >> 4) & 7, bz = t >> 7;
        x0 = bx * 32 - 8;                    // mult of 4 -> float4-aligned
        y0 = by * 64 - 9;
        const size_t zoff = (size_t)bz * (512 * 512);
        xp = xg + zoff; yp = yg + zoff;
        inter = (x0 >= 0) & (x0 + 47 < 512) & (y0 >= 0) & (y0 + 79 < 512);
    };
    auto loadItem = [&](const float* xp, const float* yp, int x0, int y0,
                        bool inter, int it, float4& xv, float4& yv) {
        const int r = it / 12, c4 = it - r * 12;
        if (inter) {
            const int o = (y0 + r) * 512 + x0 + 4 * c4;
            xv = *(const float4*)&xp[o];
            yv = *(const float4*)&yp[o];
        } else {
            const int gr = y0 + r, gc0 = x0 + 4 * c4;
            const bool rok = (unsigned)gr < 512u;
            float tx[4], ty[4];
            #pragma unroll
            for (int j = 0; j < 4; ++j) {
                const int gc = gc0 + j;
                const bool ok = rok & ((unsigned)gc < 512u);
                const int o = gr * 512 + gc;
                tx[j] = ok ? xp[o] : 0.f;
                ty[j] = ok ? yp[o] : 0.f;
            }
            xv = make_float4(tx[0], tx[1], tx[2], tx[3]);
            yv = make_float4(ty[0], ty[1], ty[2], ty[3]);
        }
    };
    auto writeItem = [&](int it, const float4& xv, const float4& yv) {
        *(uint2*)&sx[2 * it] = make_uint2(pk2(xv.x, xv.y), pk2(xv.z, xv.w));
        *(uint2*)&sy[2 * it] = make_uint2(pk2(yv.x, yv.y), pk2(yv.z, yv.w));
    };

    // ---- Tile 0: issue loads, then stage.
    int X0, Y0; const float *XP, *YP; bool I0;
    decode(t0, X0, Y0, XP, YP, I0);
    float4 ax0, ay0, ax1, ay1;
    loadItem(XP, YP, X0, Y0, I0, it0, ax0, ay0);
    if (has1) loadItem(XP, YP, X0, Y0, I0, it1, ax1, ay1);

    ldsBarrier();                            // [1] gsf visible

    // Pair-table: tbp[k] = (tap(k-19), tap(k-18)) f16x2; f16-rounded taps
    // with center correction so the f16 tap sum ~= 1. (Built while tile-0
    // loads are in flight.)
    if (tid < 64) {
        float ssum = 0.0f;
        #pragma unroll
        for (int kk = 0; kk < 11; ++kk)
            if (kk != 5) ssum += (float)(__fp16)gsf[kk];
        const __fp16 cc = (__fp16)(1.0f - ssum);
        auto tap = [&](int t) -> __fp16 {
            if ((unsigned)t > 10u) return (__fp16)0.f;
            return (t == 5) ? cc : (__fp16)gsf[t];
        };
        const int t = tid - 19;
        const unsigned short lo = __builtin_bit_cast(unsigned short, tap(t));
        const unsigned short hi = __builtin_bit_cast(unsigned short, tap(t + 1));
        tbp[tid] = (unsigned)lo | ((unsigned)hi << 16);
    }

    writeItem(it0, ax0, ay0);                // vmcnt waits inserted here
    if (has1) writeItem(it1, ax1, ay1);
    ldsBarrier();                            // [2] staging + tbp visible

    const int lane = tid & 63, wv = tid >> 6;
    const int lm = lane & 15, lg = lane >> 4;

    // Tap fragments (k = 8*lg + e): B t=k-lm-3 (base k0), C t=k-lm-4.
    f16x8 bt, afr;
    {
        const int k0 = 8 * lg - lm + 16;     // in [1,40]
        u32x4 wb, wa;
        #pragma unroll
        for (int i = 0; i < 4; ++i) {
            wb[i] = tbp[k0 + 2 * i];
            wa[i] = tbp[k0 - 1 + 2 * i];
        }
        bt  = __builtin_bit_cast(f16x8, wb);
        afr = __builtin_bit_cast(f16x8, wa);
    }

    const int rq = wv >> 1, ch = wv & 1;
    const int rpb = 8 * rq;
    const f32x4 z4 = {0.f, 0.f, 0.f, 0.f};

    // Phase B: horizontal conv, all 5 quantities, one pass.
    auto phaseB = [&]() {
        auto bitem = [&](int i) {
            const int b = i >> 1, tl = i & 1;
            const int sbase = (16 * b + lm) * SXW + 8 * tl + 4 * lg;
            const f16x8 xa = __builtin_bit_cast(f16x8, *(const u32x4*)&sx[sbase]);
            const f16x8 ya = __builtin_bit_cast(f16x8, *(const u32x4*)&sy[sbase]);
            const int ob = (16 * tl + lm) * HRP + 8 * b + 2 * lg;
            f32x4 d;
            d = mfma16(xa, bt, z4);
            *(uint2*)&hq[0][ob] = make_uint2(pk2(d[0], d[1]), pk2(d[2], d[3]));
            d = mfma16(ya, bt, z4);
            *(uint2*)&hq[1][ob] = make_uint2(pk2(d[0], d[1]), pk2(d[2], d[3]));
            d = mfma16(xa * xa, bt, z4);
            *(uint2*)&hq[2][ob] = make_uint2(pk2(d[0], d[1]), pk2(d[2], d[3]));
            d = mfma16(ya * ya, bt, z4);
            *(uint2*)&hq[3][ob] = make_uint2(pk2(d[0], d[1]), pk2(d[2], d[3]));
            d = mfma16(xa * ya, bt, z4);
            *(uint2*)&hq[4][ob] = make_uint2(pk2(d[0], d[1]), pk2(d[2], d[3]));
        };
        bitem(wv);
        if (wv < 2) bitem(wv + 8);           // wave-uniform branch
    };

    // Phase C + SSIM epilogue: returns this tile's per-lane partial.
    auto phaseC = [&]() -> float {
        const int cb = (16 * ch + lm) * HRP + rpb + 4 * lg;  // 16B aligned
        f32x4 acc[5];
        #pragma unroll
        for (int q = 0; q < 5; ++q) {
            const u32x4 w4 = *(const u32x4*)&hq[q][cb];
            acc[q] = mfma16(afr, __builtin_bit_cast(f16x8, w4), z4);
        }
        float ls = 0.0f;
        const float C1 = 1e-4f, C2 = 9e-4f;
        #pragma unroll
        for (int r = 0; r < 4; ++r) {
            const float mx = acc[0][r], my = acc[1][r];
            const float exx = acc[2][r], eyy = acc[3][r];
            const float exy = acc[4][r];
            const float mx2 = mx * mx, my2 = my * my, mxy = mx * my;
            const float vx = exx - mx2, vy = eyy - my2, vxy = exy - mxy;
            const float num = (2.0f * mxy + C1) * (2.0f * vxy + C2);
            const float den = (mx2 + my2 + C1) * (vx + vy + C2) + 1e-12f;
            ls = fmaf(num, __builtin_amdgcn_rcpf(den), ls);
        }
        return ls;
    };

    // ---- Pipeline: issue tile-1 loads, compute tile 0, stage tile 1.
    int X1, Y1; const float *XP1, *YP1; bool I1;
    decode(t1, X1, Y1, XP1, YP1, I1);
    loadItem(XP1, YP1, X1, Y1, I1, it0, ax0, ay0);   // in flight across t0
    if (has1) loadItem(XP1, YP1, X1, Y1, I1, it1, ax1, ay1);

    phaseB();                                // tile 0
    ldsBarrier();                            // [3]
    float lsum = phaseC();                   // tile 0 (reads hq)
    writeItem(it0, ax0, ay0);                // tile 1 staging (sx/sy free)
    if (has1) writeItem(it1, ax1, ay1);
    ldsBarrier();                            // [4] hq reads done, t1 staged
    phaseB();                                // tile 1
    ldsBarrier();                            // [5]
    lsum += phaseC();                        // tile 1

    // Wave reduce -> cross-wave via LDS -> ONE plain store per block.
    #pragma unroll
    for (int off = 32; off > 0; off >>= 1)
        lsum += __shfl_down(lsum, off, 64);
    if ((tid & 63) == 0) wred[tid >> 6] = lsum;
    ldsBarrier();                            // [6]
    if (tid == 0) {
        float s = 0.0f;
        #pragma unroll
        for (int w = 0; w < 8; ++w) s += wred[w];
        part[k] = s;
    }
}

__global__ __launch_bounds__(256) void ssim_reduce(
    const float* __restrict__ part, float* __restrict__ out,
    int n, float invN)
{
    __shared__ float wred[4];
    float s = 0.0f;
    for (int i = threadIdx.x; i < n; i += 256) s += part[i];
    #pragma unroll
    for (int off = 32; off > 0; off >>= 1)
        s += __shfl_down(s, off, 64);
    if ((threadIdx.x & 63) == 0) wred[threadIdx.x >> 6] = s;
    __syncthreads();
    if (threadIdx.x == 0)
        out[0] = 1.0f - (wred[0] + wred[1] + wred[2] + wred[3]) * invN;
}

extern "C" void kernel_launch(void* const* d_in, const int* in_sizes, int n_in,
                              void* d_out, int out_size, void* d_ws, size_t ws_size,
                              hipStream_t stream) {
    const float* x   = (const float*)d_in[0];
    const float* y   = (const float*)d_in[1];
    const float* w2d = (const float*)d_in[2];  // (3,1,11,11); channels identical
    float* out  = (float*)d_out;
    float* part = (float*)d_ws;                // 3072 floats = 12 KB

    const int H = 512, W = 512;
    const int total = in_sizes[0];              // 16*3*512*512
    const int Z = total / (H * W);              // 48

    dim3 grid(W / 64, H / 64, Z);               // 8 x 8 x 48 = 3072 pair-blocks
    const int npair = (W / 64) * (H / 64) * Z;
    ssim_main<<<grid, 512, 0, stream>>>(x, y, w2d, part);

    const float invN = 1.0f / (float)total;
    ssim_reduce<<<1, 256, 0, stream>>>(part, out, npair, invN);
}